// Round 1
// baseline (790.044 us; speedup 1.0000x reference)
//
#include <hip/hip_runtime.h>

// NCC loss: five 9x9x9 box sums (I, J, I^2, J^2, I*J), stride 1, pad 4,
// count_include_pad (divisor 729), ncc = cov^2/(varI*varJ+eps), out = -mean.
// Shapes fixed: [2,1,192,192,192] fp32.
//
// R8 = R7 + VALU-thinning (counters: VALUBusy 44%, HBM 14%, dur 5.6x over
// memory roofline -> issue-fat, not BW-bound):
//  (1) slice loop restructured to 2 x 18 BODYs (18 = 0 mod 2 and mod 9):
//      LDS buffer parity PB and ring index K are compile-time literals at
//      every position -> all xs4/xs1 accesses fold to immediate-offset
//      ds_read/ds_write off two hoisted base registers (was: runtime
//      (P)&1 at ~28 access sites/slice re-deriving addresses).
//  (2) EMIT divide -> v_rcp_f32 (__builtin_amdgcn_rcpf): ~9 VALU -> 1-2.
//      Term error ~2^-22 rel; final |err| ~1e-10 abs, way below tolerance.
//  (3) tree-shaped 9-tap sums (dep depth 8 -> 3-4).
//  (4) __launch_bounds__(256,4): pin VGPR<=128, keep 4 blocks/CU resident.
// Carried from R7: lgkmcnt-only slice barrier (global prefetch survives),
// xs1 stride 20 (2-way = free), named-scalar z-rings, 16x32 tile, 2 y-outs
// per thread, direct-global float4 x-phase, XCD swizzle (FETCH == 116MB
// compulsory).

#define S    192
#define SS   (S * S)
#define TX   16
#define YT   32                  // y-tile; thread (tx,tyt) owns y=2*tyt,2*tyt+1
#define NTHR 256
#define KZ   32
#define RAD  4
#define WIN  9
#define NSL  (KZ + 2 * RAD)      // 40
#define HXR  (YT + 2 * RAD)      // 40 halo rows
#define XSW  17                  // xs4 padded row stride (float4 units)
#define XSW1 20                  // xs1 padded row stride (floats): banks 8t+tx
#define NVOX (2.0 * S * S * S)

// LDS-only barrier: waves' DS ops complete (lgkmcnt) + rendezvous. No vmcnt
// drain -> global prefetch survives the barrier.
#define LDS_BARRIER() __asm__ __volatile__("s_waitcnt lgkmcnt(0)\n\ts_barrier" ::: "memory")

__global__ void ncc_init(double* ws) { ws[0] = 0.0; }

__global__ void ncc_final(const double* __restrict__ ws, float* __restrict__ out) {
    out[0] = (float)(-ws[0] / NVOX);
}

__device__ __forceinline__ float4 f4add(float4 a, float4 b) {
    return make_float4(a.x + b.x, a.y + b.y, a.z + b.z, a.w + b.w);
}
__device__ __forceinline__ float4 f4sub(float4 a, float4 b) {
    return make_float4(a.x - b.x, a.y - b.y, a.z - b.z, a.w - b.w);
}

__global__ __launch_bounds__(NTHR, 4) void ncc_main(const float* __restrict__ I,
                                                    const float* __restrict__ J,
                                                    double* __restrict__ ws) {
    // LDS ~28 KB: xs4 2*40*17*16 + xs1 2*40*20*4 + red
    __shared__ float4 xs4[2][HXR][XSW];    // (sI, sJ, sI2, sJ2)
    __shared__ float  xs1[2][HXR][XSW1];   // sIJ
    __shared__ float  red[4];

    const int tid = threadIdx.x;          // 0..255 (flat)
    const int tx  = tid & 15;
    const int tyt = tid >> 4;             // 0..15 -> outputs y=2*tyt, 2*tyt+1

    // XCD swizzle over 864 blocks: id&7 = XCD owns a 3x3 xy-patch, bijective.
    const int id  = blockIdx.x;           // 0..863
    const int xcd = id & 7;
    const int lo  = id >> 3;              // 0..107
    const int t   = lo % 9;
    const int bzq = lo / 9;               // 0..11
    const int bx  = (xcd & 3) * 3 + t % 3;     // 0..11
    const int by  = (xcd >> 2) * 3 + t / 3;    // 0..5
    const int b   = (bzq >= 6) ? 1 : 0;
    const int zc  = bzq - 6 * b;
    const int x0 = bx * TX, y0 = by * YT, z0 = zc * KZ;

    const float* Ib = I + (size_t)b * S * SS;
    const float* Jb = J + (size_t)b * S * SS;

    // x-tasks: 160 threads, task (row xr 0..39, quad xq 0..3) -> 4 x-outputs
    // from 12 input cols (4-aligned chunks, all-valid or all-invalid).
    const bool xtask = (tid < 4 * HXR);
    const int  xr  = tid >> 2;            // 0..39
    const int  xq  = tid & 3;
    const int  gy  = y0 - RAD + xr;
    const bool gyv = xtask && ((unsigned)gy < (unsigned)S);
    const int  c0  = x0 + 4 * xq - RAD;
    const bool cv0 = gyv && ((unsigned)(c0    ) < (unsigned)S);
    const bool cv1 = gyv && ((unsigned)(c0 + 4) < (unsigned)S);
    const bool cv2 = gyv && ((unsigned)(c0 + 8) < (unsigned)S);
    const ptrdiff_t rowoff = gyv ? ((ptrdiff_t)gy * S + c0) : 0;

    float4 li0, li1, li2, lj0, lj1, lj2;

    auto LOAD = [&](int p) {
        li0 = li1 = li2 = lj0 = lj1 = lj2 = make_float4(0.f, 0.f, 0.f, 0.f);
        if (p < NSL) {
            const int zi = z0 - RAD + p;
            if ((unsigned)zi < (unsigned)S) {
                const float* rI = Ib + (size_t)zi * SS + rowoff;
                const float* rJ = Jb + (size_t)zi * SS + rowoff;
                if (cv0) { li0 = *(const float4*)(rI);     lj0 = *(const float4*)(rJ); }
                if (cv1) { li1 = *(const float4*)(rI + 4); lj1 = *(const float4*)(rJ + 4); }
                if (cv2) { li2 = *(const float4*)(rI + 8); lj2 = *(const float4*)(rJ + 8); }
            }
        }
    };

    // x-phase: CB is a COMPILE-TIME literal -> all writes are immediate-offset
    // ds_write off one hoisted base.
#define XPHASE(CB) do {                                                     \
        if (xtask) {                                                        \
            const float iv[12] = { li0.x, li0.y, li0.z, li0.w,              \
                                   li1.x, li1.y, li1.z, li1.w,              \
                                   li2.x, li2.y, li2.z, li2.w };            \
            const float jv[12] = { lj0.x, lj0.y, lj0.z, lj0.w,              \
                                   lj1.x, lj1.y, lj1.z, lj1.w,              \
                                   lj2.x, lj2.y, lj2.z, lj2.w };            \
            float a = 0.f, bb = 0.f, c = 0.f, d = 0.f, e = 0.f;             \
            _Pragma("unroll")                                               \
            for (int m = 0; m < WIN; ++m) {                                 \
                a += iv[m];                                                 \
                bb += jv[m];                                                \
                c = fmaf(iv[m], iv[m], c);                                  \
                d = fmaf(jv[m], jv[m], d);                                  \
                e = fmaf(iv[m], jv[m], e);                                  \
            }                                                               \
            _Pragma("unroll")                                               \
            for (int k = 0; k < 4; ++k) {                                   \
                if (k > 0) {                                                \
                    a += iv[8 + k] - iv[k - 1];                             \
                    bb += jv[8 + k] - jv[k - 1];                            \
                    c += fmaf(iv[8 + k], iv[8 + k], -iv[k - 1] * iv[k - 1]);\
                    d += fmaf(jv[8 + k], jv[8 + k], -jv[k - 1] * jv[k - 1]);\
                    e += fmaf(iv[8 + k], jv[8 + k], -iv[k - 1] * jv[k - 1]);\
                }                                                           \
                xs4[CB][xr][4 * xq + k] = make_float4(a, bb, c, d);         \
                xs1[CB][xr][4 * xq + k] = e;                                \
            }                                                               \
        }                                                                   \
    } while (0)

    // z-rings as NAMED scalars (no arrays -> no scratch demotion possible).
    const float4 F40 = make_float4(0.f, 0.f, 0.f, 0.f);
    float4 a4_0 = F40, a4_1 = F40, a4_2 = F40, a4_3 = F40, a4_4 = F40,
           a4_5 = F40, a4_6 = F40, a4_7 = F40, a4_8 = F40;
    float  a1_0 = 0.f, a1_1 = 0.f, a1_2 = 0.f, a1_3 = 0.f, a1_4 = 0.f,
           a1_5 = 0.f, a1_6 = 0.f, a1_7 = 0.f, a1_8 = 0.f;
    float4 b4_0 = F40, b4_1 = F40, b4_2 = F40, b4_3 = F40, b4_4 = F40,
           b4_5 = F40, b4_6 = F40, b4_7 = F40, b4_8 = F40;
    float  b1_0 = 0.f, b1_1 = 0.f, b1_2 = 0.f, b1_3 = 0.f, b1_4 = 0.f,
           b1_5 = 0.f, b1_6 = 0.f, b1_7 = 0.f, b1_8 = 0.f;
    float4 runA4 = F40, runB4 = F40;
    float  runA1 = 0.f, runB1 = 0.f;
    float  acc = 0.f;
    const int yA = 2 * tyt;               // taps yA..yA+9 cover both outputs

    // One-instruction reciprocal (v_rcp_f32, ~1 ulp): final |err| ~1e-10 abs.
#define EMIT(R4, R1) do {                                                   \
        const float inv_ = 1.0f / 729.0f;                                   \
        const float mI_ = (R4).x * inv_, mJ_ = (R4).y * inv_;               \
        const float vI_ = (R4).z * inv_ - mI_ * mI_;                        \
        const float vJ_ = (R4).w * inv_ - mJ_ * mJ_;                        \
        const float cIJ_ = (R1) * inv_ - mI_ * mJ_;                         \
        acc = fmaf(cIJ_ * cIJ_,                                             \
                   __builtin_amdgcn_rcpf(vI_ * vJ_ + 1e-5f), acc);          \
    } while (0)

    // y-phase for slice with STATIC buffer parity PB and STATIC ring slot K.
    // 10 b128 + 10 b32 immediate-offset ds_reads; tree-shaped 9-tap sums.
#define YSTEP(PB, K, DOEMIT) do {                                           \
        const float4 r0 = xs4[PB][yA + 0][tx];                              \
        const float4 r1 = xs4[PB][yA + 1][tx];                              \
        const float4 r2 = xs4[PB][yA + 2][tx];                              \
        const float4 r3 = xs4[PB][yA + 3][tx];                              \
        const float4 r4 = xs4[PB][yA + 4][tx];                              \
        const float4 r5 = xs4[PB][yA + 5][tx];                              \
        const float4 r6 = xs4[PB][yA + 6][tx];                              \
        const float4 r7 = xs4[PB][yA + 7][tx];                              \
        const float4 r8 = xs4[PB][yA + 8][tx];                              \
        const float4 r9 = xs4[PB][yA + 9][tx];                              \
        const float  q0 = xs1[PB][yA + 0][tx];                              \
        const float  q1 = xs1[PB][yA + 1][tx];                              \
        const float  q2 = xs1[PB][yA + 2][tx];                              \
        const float  q3 = xs1[PB][yA + 3][tx];                              \
        const float  q4 = xs1[PB][yA + 4][tx];                              \
        const float  q5 = xs1[PB][yA + 5][tx];                              \
        const float  q6 = xs1[PB][yA + 6][tx];                              \
        const float  q7 = xs1[PB][yA + 7][tx];                              \
        const float  q8 = xs1[PB][yA + 8][tx];                              \
        const float  q9 = xs1[PB][yA + 9][tx];                              \
        const float4 s4v = f4add(f4add(f4add(f4add(r0, r1), f4add(r2, r3)), \
                                       f4add(f4add(r4, r5), f4add(r6, r7))),\
                                 r8);                                       \
        const float  s1v = (((q0 + q1) + (q2 + q3)) +                       \
                            ((q4 + q5) + (q6 + q7))) + q8;                  \
        const float4 sB4 = f4add(f4sub(s4v, r0), r9);                       \
        const float  sB1 = s1v - q0 + q9;                                   \
        runA4 = f4add(runA4, f4sub(s4v, a4_##K));   a4_##K = s4v;           \
        runA1 += s1v - a1_##K;                      a1_##K = s1v;           \
        runB4 = f4add(runB4, f4sub(sB4, b4_##K));   b4_##K = sB4;           \
        runB1 += sB1 - b1_##K;                      b1_##K = sB1;           \
        if (DOEMIT) { EMIT(runA4, runA1); EMIT(runB4, runB1); }             \
    } while (0)

    // BODY position p = idx-1: y(p) | x(p+1) | load(p+2) | lds-barrier.
    // PB = p&1 and K = p%9 are literals per position.
#define BODY(PB, K, DOEMIT) do {                                            \
        YSTEP(PB, K, DOEMIT);                                               \
        XPHASE((PB) ^ 1);                                                   \
        LOAD(idx + 1);                                                      \
        LDS_BARRIER();                                                      \
        ++idx;                                                              \
    } while (0)

    // Pipeline prologue.
    LOAD(0);
    XPHASE(0);
    LOAD(1);
    LDS_BARRIER();

    // Main loop: 2 groups of 18 BODYs (18 = 0 mod 2 and mod 9 -> parity and
    // ring slot are static per position; group g covers p = 18g .. 18g+17).
    // Emit starts at p = 2*RAD = 8: static true for pos 8..17, uniform
    // scalar bool (g != 0) for pos 0..7.
    int idx = 1;
    #pragma unroll 1
    for (int g = 0; g < 2; ++g) {
        const bool em = (g != 0);
        BODY(0, 0, em);   BODY(1, 1, em);   BODY(0, 2, em);   BODY(1, 3, em);
        BODY(0, 4, em);   BODY(1, 5, em);   BODY(0, 6, em);   BODY(1, 7, em);
        BODY(0, 8, true); BODY(1, 0, true); BODY(0, 1, true); BODY(1, 2, true);
        BODY(0, 3, true); BODY(1, 4, true); BODY(0, 5, true); BODY(1, 6, true);
        BODY(0, 7, true); BODY(1, 8, true);
    }
    // Tail: p = 36, 37, 38, then final y-only step p = 39 (39%9 = 3, odd).
    BODY(0, 0, true);
    BODY(1, 1, true);
    BODY(0, 2, true);
    YSTEP(1, 3, true);
#undef BODY
#undef YSTEP
#undef EMIT
#undef XPHASE

    // Block reduction: wave shuffle -> LDS -> one double atomic.
    // (Full __syncthreads here is fine: once per block, nothing to prefetch.)
    float v = acc;
    #pragma unroll
    for (int off = 32; off >= 1; off >>= 1)
        v += __shfl_down(v, off, 64);
    const int lane = tid & 63;
    const int wid  = tid >> 6;
    if (lane == 0) red[wid] = v;
    __syncthreads();
    if (tid == 0) {
        atomicAdd(ws, (double)(red[0] + red[1] + red[2] + red[3]));
    }
}

extern "C" void kernel_launch(void* const* d_in, const int* in_sizes, int n_in,
                              void* d_out, int out_size, void* d_ws, size_t ws_size,
                              hipStream_t stream) {
    const float* I = (const float*)d_in[0];   // y_pred
    const float* J = (const float*)d_in[1];   // y_true
    double* ws = (double*)d_ws;
    float* out = (float*)d_out;

    hipLaunchKernelGGL(ncc_init, dim3(1), dim3(1), 0, stream, ws);

    hipLaunchKernelGGL(ncc_main, dim3(12 * 6 * 12), dim3(NTHR), 0, stream,
                       I, J, ws);

    hipLaunchKernelGGL(ncc_final, dim3(1), dim3(1), 0, stream, ws, out);
}

// Round 2
// 527.795 us; speedup vs baseline: 1.4969x; 1.4969x over previous
//
#include <hip/hip_runtime.h>

// NCC loss: five 9x9x9 box sums (I, J, I^2, J^2, I*J), stride 1, pad 4,
// count_include_pad (divisor 729), ncc = cov^2/(varI*varJ+eps), out = -mean.
// Shapes fixed: [2,1,192,192,192] fp32.
//
// R9 = R8 with the occupancy bound reverted to R7's (256,2).
// R8 POST-MORTEM: __launch_bounds__(256,4) made the compiler allocate 64
// VGPRs for ~130 floats of live state (two 9-deep z-rings + prefetch) ->
// everything spilled to scratch: WRITE_SIZE 2MB -> 1.3GB, FETCH 116MB ->
// 878MB, dur 108 -> 705us. The kernel was spill-BW-bound, not VALU-thin.
// With (256,2) the allocator has 256 VGPRs of headroom (R7 used 128).
//
// Kept from R8 (the VALU-thinning, verified correct via absmax=0):
//  (1) slice loop as 2 x 18 BODYs (18 = 0 mod 2 and mod 9): LDS buffer
//      parity PB and ring slot K are compile-time literals everywhere ->
//      xs4/xs1 accesses fold to immediate-offset ds_read/ds_write off
//      hoisted base registers (no per-access address re-derivation).
//  (2) EMIT divide -> v_rcp_f32 (~9 VALU -> 1-2); |err| ~1e-10 abs.
//  (3) tree-shaped 9-tap sums (dep depth 8 -> 3-4).
// Carried from R7: lgkmcnt-only slice barrier (global prefetch survives),
// xs1 stride 20 (2-way = free), named-scalar z-rings, 16x32 tile, 2 y-outs
// per thread, direct-global float4 x-phase, XCD swizzle (FETCH == 116MB
// compulsory).

#define S    192
#define SS   (S * S)
#define TX   16
#define YT   32                  // y-tile; thread (tx,tyt) owns y=2*tyt,2*tyt+1
#define NTHR 256
#define KZ   32
#define RAD  4
#define WIN  9
#define NSL  (KZ + 2 * RAD)      // 40
#define HXR  (YT + 2 * RAD)      // 40 halo rows
#define XSW  17                  // xs4 padded row stride (float4 units)
#define XSW1 20                  // xs1 padded row stride (floats): banks 8t+tx
#define NVOX (2.0 * S * S * S)

// LDS-only barrier: waves' DS ops complete (lgkmcnt) + rendezvous. No vmcnt
// drain -> global prefetch survives the barrier.
#define LDS_BARRIER() __asm__ __volatile__("s_waitcnt lgkmcnt(0)\n\ts_barrier" ::: "memory")

__global__ void ncc_init(double* ws) { ws[0] = 0.0; }

__global__ void ncc_final(const double* __restrict__ ws, float* __restrict__ out) {
    out[0] = (float)(-ws[0] / NVOX);
}

__device__ __forceinline__ float4 f4add(float4 a, float4 b) {
    return make_float4(a.x + b.x, a.y + b.y, a.z + b.z, a.w + b.w);
}
__device__ __forceinline__ float4 f4sub(float4 a, float4 b) {
    return make_float4(a.x - b.x, a.y - b.y, a.z - b.z, a.w - b.w);
}

__global__ __launch_bounds__(NTHR, 2) void ncc_main(const float* __restrict__ I,
                                                    const float* __restrict__ J,
                                                    double* __restrict__ ws) {
    // LDS ~28 KB: xs4 2*40*17*16 + xs1 2*40*20*4 + red
    __shared__ float4 xs4[2][HXR][XSW];    // (sI, sJ, sI2, sJ2)
    __shared__ float  xs1[2][HXR][XSW1];   // sIJ
    __shared__ float  red[4];

    const int tid = threadIdx.x;          // 0..255 (flat)
    const int tx  = tid & 15;
    const int tyt = tid >> 4;             // 0..15 -> outputs y=2*tyt, 2*tyt+1

    // XCD swizzle over 864 blocks: id&7 = XCD owns a 3x3 xy-patch, bijective.
    const int id  = blockIdx.x;           // 0..863
    const int xcd = id & 7;
    const int lo  = id >> 3;              // 0..107
    const int t   = lo % 9;
    const int bzq = lo / 9;               // 0..11
    const int bx  = (xcd & 3) * 3 + t % 3;     // 0..11
    const int by  = (xcd >> 2) * 3 + t / 3;    // 0..5
    const int b   = (bzq >= 6) ? 1 : 0;
    const int zc  = bzq - 6 * b;
    const int x0 = bx * TX, y0 = by * YT, z0 = zc * KZ;

    const float* Ib = I + (size_t)b * S * SS;
    const float* Jb = J + (size_t)b * S * SS;

    // x-tasks: 160 threads, task (row xr 0..39, quad xq 0..3) -> 4 x-outputs
    // from 12 input cols (4-aligned chunks, all-valid or all-invalid).
    const bool xtask = (tid < 4 * HXR);
    const int  xr  = tid >> 2;            // 0..39
    const int  xq  = tid & 3;
    const int  gy  = y0 - RAD + xr;
    const bool gyv = xtask && ((unsigned)gy < (unsigned)S);
    const int  c0  = x0 + 4 * xq - RAD;
    const bool cv0 = gyv && ((unsigned)(c0    ) < (unsigned)S);
    const bool cv1 = gyv && ((unsigned)(c0 + 4) < (unsigned)S);
    const bool cv2 = gyv && ((unsigned)(c0 + 8) < (unsigned)S);
    const ptrdiff_t rowoff = gyv ? ((ptrdiff_t)gy * S + c0) : 0;

    float4 li0, li1, li2, lj0, lj1, lj2;

    auto LOAD = [&](int p) {
        li0 = li1 = li2 = lj0 = lj1 = lj2 = make_float4(0.f, 0.f, 0.f, 0.f);
        if (p < NSL) {
            const int zi = z0 - RAD + p;
            if ((unsigned)zi < (unsigned)S) {
                const float* rI = Ib + (size_t)zi * SS + rowoff;
                const float* rJ = Jb + (size_t)zi * SS + rowoff;
                if (cv0) { li0 = *(const float4*)(rI);     lj0 = *(const float4*)(rJ); }
                if (cv1) { li1 = *(const float4*)(rI + 4); lj1 = *(const float4*)(rJ + 4); }
                if (cv2) { li2 = *(const float4*)(rI + 8); lj2 = *(const float4*)(rJ + 8); }
            }
        }
    };

    // x-phase: CB is a COMPILE-TIME literal -> all writes are immediate-offset
    // ds_write off one hoisted base.
#define XPHASE(CB) do {                                                     \
        if (xtask) {                                                        \
            const float iv[12] = { li0.x, li0.y, li0.z, li0.w,              \
                                   li1.x, li1.y, li1.z, li1.w,              \
                                   li2.x, li2.y, li2.z, li2.w };            \
            const float jv[12] = { lj0.x, lj0.y, lj0.z, lj0.w,              \
                                   lj1.x, lj1.y, lj1.z, lj1.w,              \
                                   lj2.x, lj2.y, lj2.z, lj2.w };            \
            float a = 0.f, bb = 0.f, c = 0.f, d = 0.f, e = 0.f;             \
            _Pragma("unroll")                                               \
            for (int m = 0; m < WIN; ++m) {                                 \
                a += iv[m];                                                 \
                bb += jv[m];                                                \
                c = fmaf(iv[m], iv[m], c);                                  \
                d = fmaf(jv[m], jv[m], d);                                  \
                e = fmaf(iv[m], jv[m], e);                                  \
            }                                                               \
            _Pragma("unroll")                                               \
            for (int k = 0; k < 4; ++k) {                                   \
                if (k > 0) {                                                \
                    a += iv[8 + k] - iv[k - 1];                             \
                    bb += jv[8 + k] - jv[k - 1];                            \
                    c += fmaf(iv[8 + k], iv[8 + k], -iv[k - 1] * iv[k - 1]);\
                    d += fmaf(jv[8 + k], jv[8 + k], -jv[k - 1] * jv[k - 1]);\
                    e += fmaf(iv[8 + k], jv[8 + k], -iv[k - 1] * jv[k - 1]);\
                }                                                           \
                xs4[CB][xr][4 * xq + k] = make_float4(a, bb, c, d);         \
                xs1[CB][xr][4 * xq + k] = e;                                \
            }                                                               \
        }                                                                   \
    } while (0)

    // z-rings as NAMED scalars (no arrays -> no scratch demotion possible).
    const float4 F40 = make_float4(0.f, 0.f, 0.f, 0.f);
    float4 a4_0 = F40, a4_1 = F40, a4_2 = F40, a4_3 = F40, a4_4 = F40,
           a4_5 = F40, a4_6 = F40, a4_7 = F40, a4_8 = F40;
    float  a1_0 = 0.f, a1_1 = 0.f, a1_2 = 0.f, a1_3 = 0.f, a1_4 = 0.f,
           a1_5 = 0.f, a1_6 = 0.f, a1_7 = 0.f, a1_8 = 0.f;
    float4 b4_0 = F40, b4_1 = F40, b4_2 = F40, b4_3 = F40, b4_4 = F40,
           b4_5 = F40, b4_6 = F40, b4_7 = F40, b4_8 = F40;
    float  b1_0 = 0.f, b1_1 = 0.f, b1_2 = 0.f, b1_3 = 0.f, b1_4 = 0.f,
           b1_5 = 0.f, b1_6 = 0.f, b1_7 = 0.f, b1_8 = 0.f;
    float4 runA4 = F40, runB4 = F40;
    float  runA1 = 0.f, runB1 = 0.f;
    float  acc = 0.f;
    const int yA = 2 * tyt;               // taps yA..yA+9 cover both outputs

    // One-instruction reciprocal (v_rcp_f32, ~1 ulp): final |err| ~1e-10 abs.
#define EMIT(R4, R1) do {                                                   \
        const float inv_ = 1.0f / 729.0f;                                   \
        const float mI_ = (R4).x * inv_, mJ_ = (R4).y * inv_;               \
        const float vI_ = (R4).z * inv_ - mI_ * mI_;                        \
        const float vJ_ = (R4).w * inv_ - mJ_ * mJ_;                        \
        const float cIJ_ = (R1) * inv_ - mI_ * mJ_;                         \
        acc = fmaf(cIJ_ * cIJ_,                                             \
                   __builtin_amdgcn_rcpf(vI_ * vJ_ + 1e-5f), acc);          \
    } while (0)

    // y-phase for slice with STATIC buffer parity PB and STATIC ring slot K.
    // 10 b128 + 10 b32 immediate-offset ds_reads; tree-shaped 9-tap sums.
#define YSTEP(PB, K, DOEMIT) do {                                           \
        const float4 r0 = xs4[PB][yA + 0][tx];                              \
        const float4 r1 = xs4[PB][yA + 1][tx];                              \
        const float4 r2 = xs4[PB][yA + 2][tx];                              \
        const float4 r3 = xs4[PB][yA + 3][tx];                              \
        const float4 r4 = xs4[PB][yA + 4][tx];                              \
        const float4 r5 = xs4[PB][yA + 5][tx];                              \
        const float4 r6 = xs4[PB][yA + 6][tx];                              \
        const float4 r7 = xs4[PB][yA + 7][tx];                              \
        const float4 r8 = xs4[PB][yA + 8][tx];                              \
        const float4 r9 = xs4[PB][yA + 9][tx];                              \
        const float  q0 = xs1[PB][yA + 0][tx];                              \
        const float  q1 = xs1[PB][yA + 1][tx];                              \
        const float  q2 = xs1[PB][yA + 2][tx];                              \
        const float  q3 = xs1[PB][yA + 3][tx];                              \
        const float  q4 = xs1[PB][yA + 4][tx];                              \
        const float  q5 = xs1[PB][yA + 5][tx];                              \
        const float  q6 = xs1[PB][yA + 6][tx];                              \
        const float  q7 = xs1[PB][yA + 7][tx];                              \
        const float  q8 = xs1[PB][yA + 8][tx];                              \
        const float  q9 = xs1[PB][yA + 9][tx];                              \
        const float4 s4v = f4add(f4add(f4add(f4add(r0, r1), f4add(r2, r3)), \
                                       f4add(f4add(r4, r5), f4add(r6, r7))),\
                                 r8);                                       \
        const float  s1v = (((q0 + q1) + (q2 + q3)) +                       \
                            ((q4 + q5) + (q6 + q7))) + q8;                  \
        const float4 sB4 = f4add(f4sub(s4v, r0), r9);                       \
        const float  sB1 = s1v - q0 + q9;                                   \
        runA4 = f4add(runA4, f4sub(s4v, a4_##K));   a4_##K = s4v;           \
        runA1 += s1v - a1_##K;                      a1_##K = s1v;           \
        runB4 = f4add(runB4, f4sub(sB4, b4_##K));   b4_##K = sB4;           \
        runB1 += sB1 - b1_##K;                      b1_##K = sB1;           \
        if (DOEMIT) { EMIT(runA4, runA1); EMIT(runB4, runB1); }             \
    } while (0)

    // BODY position p = idx-1: y(p) | x(p+1) | load(p+2) | lds-barrier.
    // PB = p&1 and K = p%9 are literals per position.
#define BODY(PB, K, DOEMIT) do {                                            \
        YSTEP(PB, K, DOEMIT);                                               \
        XPHASE((PB) ^ 1);                                                   \
        LOAD(idx + 1);                                                      \
        LDS_BARRIER();                                                      \
        ++idx;                                                              \
    } while (0)

    // Pipeline prologue.
    LOAD(0);
    XPHASE(0);
    LOAD(1);
    LDS_BARRIER();

    // Main loop: 2 groups of 18 BODYs (18 = 0 mod 2 and mod 9 -> parity and
    // ring slot are static per position; group g covers p = 18g .. 18g+17).
    // Emit starts at p = 2*RAD = 8: static true for pos 8..17, uniform
    // scalar bool (g != 0) for pos 0..7.
    int idx = 1;
    #pragma unroll 1
    for (int g = 0; g < 2; ++g) {
        const bool em = (g != 0);
        BODY(0, 0, em);   BODY(1, 1, em);   BODY(0, 2, em);   BODY(1, 3, em);
        BODY(0, 4, em);   BODY(1, 5, em);   BODY(0, 6, em);   BODY(1, 7, em);
        BODY(0, 8, true); BODY(1, 0, true); BODY(0, 1, true); BODY(1, 2, true);
        BODY(0, 3, true); BODY(1, 4, true); BODY(0, 5, true); BODY(1, 6, true);
        BODY(0, 7, true); BODY(1, 8, true);
    }
    // Tail: p = 36, 37, 38, then final y-only step p = 39 (39%9 = 3, odd).
    BODY(0, 0, true);
    BODY(1, 1, true);
    BODY(0, 2, true);
    YSTEP(1, 3, true);
#undef BODY
#undef YSTEP
#undef EMIT
#undef XPHASE

    // Block reduction: wave shuffle -> LDS -> one double atomic.
    // (Full __syncthreads here is fine: once per block, nothing to prefetch.)
    float v = acc;
    #pragma unroll
    for (int off = 32; off >= 1; off >>= 1)
        v += __shfl_down(v, off, 64);
    const int lane = tid & 63;
    const int wid  = tid >> 6;
    if (lane == 0) red[wid] = v;
    __syncthreads();
    if (tid == 0) {
        atomicAdd(ws, (double)(red[0] + red[1] + red[2] + red[3]));
    }
}

extern "C" void kernel_launch(void* const* d_in, const int* in_sizes, int n_in,
                              void* d_out, int out_size, void* d_ws, size_t ws_size,
                              hipStream_t stream) {
    const float* I = (const float*)d_in[0];   // y_pred
    const float* J = (const float*)d_in[1];   // y_true
    double* ws = (double*)d_ws;
    float* out = (float*)d_out;

    hipLaunchKernelGGL(ncc_init, dim3(1), dim3(1), 0, stream, ws);

    hipLaunchKernelGGL(ncc_main, dim3(12 * 6 * 12), dim3(NTHR), 0, stream,
                       I, J, ws);

    hipLaunchKernelGGL(ncc_final, dim3(1), dim3(1), 0, stream, ws, out);
}